// Round 4
// baseline (26.504 us; speedup 1.0000x reference)
//
#include <hip/hip_runtime.h>
#include <hip/hip_bf16.h>

// B=64, C=512, Q=64, D=512, fp32 in/out.
// out[b,c,q] = sum_d H[b,c,d] * U'[b,q,d] + s_u[b,q]
//   U'[q,d] = w_hu[d]*U[q,d] + w_h[d]   (folds s_h into the GEMM)
//   s_u[q]  = sum_d w_u[d]*U[q,d]
// Kernel 1 (prep): U -> U' (bf16, fragment-ordered) + s_u, into d_ws.
// Kernel 2 (gemm): 2-wave blocks K-split (wave w owns d in [w*256,(w+1)*256));
//   partial accumulators combined via LDS + one barrier. 4096 waves total
//   -> 4 waves/SIMD (2x round-3) to hide HBM latency on the H stream.
//
// ws layout (bytes):
//   [0, 4 MB)        : U' bf16, elem(b,d,q) at b*32768 + (d>>5)*2048
//                      + ((d>>3)&3)*512 + q*8 + (d&7)
//   [4 MB, 4 MB+16K) : s_u fp32 [b][q]

#define Bn 64
#define Cn 512
#define Qn 64
#define Dn 512
#define WS_SU_OFF (4u * 1024u * 1024u)

typedef __bf16 bf16x8 __attribute__((ext_vector_type(8)));
typedef float  f32x4  __attribute__((ext_vector_type(4)));

// ---------------------------------------------------------------- prep ----
__global__ __launch_bounds__(256)
void prep_kernel(const float* __restrict__ U, const float* __restrict__ w,
                 __bf16* __restrict__ wu_out, float* __restrict__ su_out)
{
    const int bid = (int)blockIdx.x;      // 256 blocks
    const int b   = bid >> 2;
    const int qg  = bid & 3;
    const int t   = (int)threadIdx.x;
    const int q   = qg * 16 + (t >> 4);
    const int seg = t & 15;

    const float* __restrict__ Uq = U + ((size_t)(b * Qn + q)) * Dn;
    __bf16* __restrict__ wb = wu_out + (size_t)b * 32768;

    float su = 0.f;
#pragma unroll
    for (int j = 0; j < 4; ++j) {
        const int d0 = seg * 32 + j * 8;
        f32x4 u0  = *(const f32x4*)(Uq + d0);
        f32x4 u1  = *(const f32x4*)(Uq + d0 + 4);
        f32x4 wh0 = *(const f32x4*)(w + d0);
        f32x4 wh1 = *(const f32x4*)(w + d0 + 4);
        f32x4 wu0 = *(const f32x4*)(w + 512 + d0);
        f32x4 wu1 = *(const f32x4*)(w + 512 + d0 + 4);
        f32x4 wm0 = *(const f32x4*)(w + 1024 + d0);
        f32x4 wm1 = *(const f32x4*)(w + 1024 + d0 + 4);
        bf16x8 v;
#pragma unroll
        for (int i = 0; i < 4; ++i) {
            su += wu0[i] * u0[i] + wu1[i] * u1[i];
            v[i]     = (__bf16)__builtin_fmaf(wm0[i], u0[i], wh0[i]);
            v[i + 4] = (__bf16)__builtin_fmaf(wm1[i], u1[i], wh1[i]);
        }
        *(bf16x8*)(wb + seg * 2048 + j * 512 + q * 8) = v;
    }
    su += __shfl_xor(su, 1);
    su += __shfl_xor(su, 2);
    su += __shfl_xor(su, 4);
    su += __shfl_xor(su, 8);
    if (seg == 0) su_out[b * Qn + q] = su;
}

// ---------------------------------------------------------------- gemm ----
__global__ __launch_bounds__(128, 4)
void gemm_kernel(const float* __restrict__ H, const __bf16* __restrict__ Uw,
                 const float* __restrict__ suw, float* __restrict__ out)
{
    __shared__ f32x4 comb[4][64];   // wave1's partial accumulators (4 KB)

    // XCD swizzle: XCD x (= bid%8) owns batches 8x..8x+7, all 32 c-blocks,
    // so U'[b] (64 KB) stays warm in that XCD's L2/L3.
    const int r  = (int)blockIdx.x;          // 2048 blocks x 128 threads
    const int b  = (r & 7) * 8 + ((r >> 3) & 7);
    const int cb = r >> 6;                   // 0..31

    const int t    = (int)threadIdx.x;
    const int w    = t >> 6;                 // k-half: 0 -> d<256, 1 -> d>=256
    const int lane = t & 63;
    const int ql   = lane & 15;
    const int hh   = lane >> 4;

    const float*  __restrict__ hp =
        H + ((size_t)(b * Cn + cb * 16 + ql)) * Dn + w * 256 + hh * 8;
    const __bf16* __restrict__ up =
        Uw + (size_t)b * 32768 + w * 8 * 2048 + hh * 512 + ql * 8;

    // ring-3 / lead-3 prefetch on both streams; 8 k-steps per wave.
    f32x4  ha[3], hb[3];
    bf16x8 uf[3][4];

#pragma unroll
    for (int p = 0; p < 3; ++p) {
        ha[p] = *(const f32x4*)(hp + 32 * p);
        hb[p] = *(const f32x4*)(hp + 32 * p + 4);
#pragma unroll
        for (int n = 0; n < 4; ++n)
            uf[p][n] = *(const bf16x8*)(up + p * 2048 + n * 128);
    }

    f32x4 acc[4] = {{0.f,0.f,0.f,0.f},{0.f,0.f,0.f,0.f},
                    {0.f,0.f,0.f,0.f},{0.f,0.f,0.f,0.f}};

#pragma unroll
    for (int k = 0; k < 8; ++k) {            // fully unrolled, static regs
        f32x4 ca = ha[k % 3], cb2 = hb[k % 3];
        bf16x8 ub[4];
#pragma unroll
        for (int n = 0; n < 4; ++n) ub[n] = uf[k % 3][n];
        if (k + 3 < 8) {
            ha[k % 3] = *(const f32x4*)(hp + 32 * (k + 3));
            hb[k % 3] = *(const f32x4*)(hp + 32 * (k + 3) + 4);
#pragma unroll
            for (int n = 0; n < 4; ++n)
                uf[k % 3][n] = *(const bf16x8*)(up + (k + 3) * 2048 + n * 128);
        }
        bf16x8 a;
#pragma unroll
        for (int i = 0; i < 4; ++i) {
            a[i]     = (__bf16)ca[i];
            a[i + 4] = (__bf16)cb2[i];
        }
#pragma unroll
        for (int n = 0; n < 4; ++n)
            acc[n] = __builtin_amdgcn_mfma_f32_16x16x32_bf16(a, ub[n], acc[n], 0, 0, 0);
    }

    // ---- combine the two K-halves through LDS ----
    if (w == 1) {
#pragma unroll
        for (int n = 0; n < 4; ++n) comb[n][lane] = acc[n];
    }
    __syncthreads();
    if (w == 1) return;

#pragma unroll
    for (int n = 0; n < 4; ++n) {
        f32x4 c2 = comb[n][lane];
#pragma unroll
        for (int rr = 0; rr < 4; ++rr) acc[n][rr] += c2[rr];
    }

    // ---- epilogue (wave0 only): out[c,q] = acc + s_u[q] ----
    const float* __restrict__ sup  = suw + b * Qn;
    float*       __restrict__ outb = out + ((size_t)(b * Cn + cb * 16)) * Qn;
#pragma unroll
    for (int n = 0; n < 4; ++n) {
        const int q = n * 16 + ql;
        const float s = sup[q];
#pragma unroll
        for (int rr = 0; rr < 4; ++rr)
            outb[(size_t)(hh * 4 + rr) * Qn + q] = acc[n][rr] + s;
    }
}

extern "C" void kernel_launch(void* const* d_in, const int* in_sizes, int n_in,
                              void* d_out, int out_size, void* d_ws, size_t ws_size,
                              hipStream_t stream) {
    const float* H = (const float*)d_in[0];
    const float* U = (const float*)d_in[1];
    const float* w = (const float*)d_in[2];
    float* out = (float*)d_out;

    __bf16* ws_u  = (__bf16*)d_ws;
    float*  ws_su = (float*)((char*)d_ws + WS_SU_OFF);

    prep_kernel<<<dim3(256), dim3(256), 0, stream>>>(U, w, ws_u, ws_su);
    gemm_kernel<<<dim3(2048), dim3(128), 0, stream>>>(H, ws_u, ws_su, out);
}

// Round 5
// 20.911 us; speedup vs baseline: 1.2675x; 1.2675x over previous
//
#include <hip/hip_runtime.h>
#include <hip/hip_bf16.h>

// B=64, C=512, Q=64, D=512, fp32 in/out.
// out[b,c,q] = sum_d H[b,c,d]*U'[b,q,d] + s_u[b,q]
//   U'[q,d] = w_hu[d]*U[q,d] + w_h[d]   (folds s_h into the GEMM)
//   s_u[q]  = sum_d w_u[d]*U[q,d]
// Single fused kernel: 256 blocks (1/CU) x 512 threads (8 waves).
// Block = (batch b, 128 c-rows). Stage U'[b] (bf16, 64 KB) ONCE into LDS
// with XOR-swizzled q-position (p = q ^ (kt&7)) -> conflict-free b128
// stores AND reads. One barrier; then a barrier-free K-loop: H streams
// global->reg->cvt->MFMA with ring-4 prefetch.

#define Bn 64
#define Cn 512
#define Qn 64
#define Dn 512

typedef __bf16 bf16x8 __attribute__((ext_vector_type(8)));
typedef float  f32x4  __attribute__((ext_vector_type(4)));

__global__ __launch_bounds__(512, 1)
void sim_kernel(const float* __restrict__ H, const float* __restrict__ U,
                const float* __restrict__ w, float* __restrict__ out)
{
    // Us[kt][hh][p][j]: element d = kt*32 + hh*8 + j of q with (q ^ (kt&7)) == p
    __shared__ __bf16 Us[16][4][64][8];   // 64 KB
    __shared__ float  su_l[Qn];

    // XCD-contiguous mapping: XCD x (= bid&7) owns batches 8x..8x+7
    // (4 blocks per batch, 128 c-rows each) -> U[b] L2-local during staging.
    const int r  = (int)blockIdx.x;       // 0..255
    const int x  = r & 7;
    const int i  = r >> 3;                // 0..31
    const int b  = x * 8 + (i >> 2);
    const int c0 = (i & 3) * 128;

    const int t    = (int)threadIdx.x;
    const int wv   = t >> 6;              // wave 0..7: rows c0+wv*16..+15
    const int lane = t & 63;
    const int ql   = lane & 15;
    const int hh   = lane >> 4;

    // ---- H ring prologue: issued FIRST (oldest in the VMEM FIFO, so the
    // staging loads' waits never add stalls on top of them) ----
    const float* __restrict__ hp =
        H + ((size_t)(b * Cn + c0 + wv * 16 + ql)) * Dn + hh * 8;
    f32x4 ha[4], hb[4];
#pragma unroll
    for (int p = 0; p < 3; ++p) {
        ha[p] = *(const f32x4*)(hp + 32 * p);
        hb[p] = *(const f32x4*)(hp + 32 * p + 4);
    }

    // ---- Phase 1: stage U' once (w held in registers; 28 loads/thread) ----
    {
        const int dk = t & 31;            // 16-float d-chunk
        const int qg = t >> 5;            // 0..15 -> q in {4qg..4qg+3}
        const int kt = dk >> 1;
        const int cs = kt & 7;            // q-position swizzle
        float su_p[4] = {0.f, 0.f, 0.f, 0.f};
#pragma unroll
        for (int half = 0; half < 2; ++half) {
            const int d0 = dk * 16 + half * 8;
            const int hv = (dk & 1) * 2 + half;
            f32x4 wh0 = *(const f32x4*)(w + d0);
            f32x4 wh1 = *(const f32x4*)(w + d0 + 4);
            f32x4 wu0 = *(const f32x4*)(w + 512 + d0);
            f32x4 wu1 = *(const f32x4*)(w + 512 + d0 + 4);
            f32x4 wm0 = *(const f32x4*)(w + 1024 + d0);
            f32x4 wm1 = *(const f32x4*)(w + 1024 + d0 + 4);
#pragma unroll
            for (int qi = 0; qi < 4; ++qi) {
                const int q = qg * 4 + qi;
                const float* __restrict__ Uq =
                    U + ((size_t)(b * Qn + q)) * Dn + d0;
                f32x4 u0 = *(const f32x4*)Uq;
                f32x4 u1 = *(const f32x4*)(Uq + 4);
                bf16x8 v;
#pragma unroll
                for (int e = 0; e < 4; ++e) {
                    su_p[qi] += wu0[e] * u0[e] + wu1[e] * u1[e];
                    v[e]     = (__bf16)__builtin_fmaf(wm0[e], u0[e], wh0[e]);
                    v[e + 4] = (__bf16)__builtin_fmaf(wm1[e], u1[e], wh1[e]);
                }
                *(bf16x8*)&Us[kt][hv][q ^ cs][0] = v;
            }
        }
        // s_u: reduce over the 32 d-chunks (dk == lane&31)
#pragma unroll
        for (int qi = 0; qi < 4; ++qi) {
            float v = su_p[qi];
            v += __shfl_xor(v, 1);
            v += __shfl_xor(v, 2);
            v += __shfl_xor(v, 4);
            v += __shfl_xor(v, 8);
            v += __shfl_xor(v, 16);
            if (dk == 0) su_l[qg * 4 + qi] = v;
        }
    }

    __syncthreads();   // the ONLY barrier

    // ---- Phase 2: barrier-free K-loop (16 steps, fully unrolled) ----
    f32x4 acc[4] = {{0.f,0.f,0.f,0.f},{0.f,0.f,0.f,0.f},
                    {0.f,0.f,0.f,0.f},{0.f,0.f,0.f,0.f}};

#pragma unroll
    for (int k = 0; k < 16; ++k) {
        f32x4 ca = ha[k & 3], cb = hb[k & 3];
        if (k + 3 < 16) {
            ha[(k + 3) & 3] = *(const f32x4*)(hp + 32 * (k + 3));
            hb[(k + 3) & 3] = *(const f32x4*)(hp + 32 * (k + 3) + 4);
        }
        bf16x8 a;
#pragma unroll
        for (int e = 0; e < 4; ++e) {
            a[e]     = (__bf16)ca[e];
            a[e + 4] = (__bf16)cb[e];
        }
        const int pq = ql ^ (k & 7);      // un-swizzle (1 v_xor per step)
        bf16x8 f0 = *(const bf16x8*)&Us[k][hh][pq +  0][0];
        bf16x8 f1 = *(const bf16x8*)&Us[k][hh][pq + 16][0];
        bf16x8 f2 = *(const bf16x8*)&Us[k][hh][pq + 32][0];
        bf16x8 f3 = *(const bf16x8*)&Us[k][hh][pq + 48][0];
        acc[0] = __builtin_amdgcn_mfma_f32_16x16x32_bf16(a, f0, acc[0], 0, 0, 0);
        acc[1] = __builtin_amdgcn_mfma_f32_16x16x32_bf16(a, f1, acc[1], 0, 0, 0);
        acc[2] = __builtin_amdgcn_mfma_f32_16x16x32_bf16(a, f2, acc[2], 0, 0, 0);
        acc[3] = __builtin_amdgcn_mfma_f32_16x16x32_bf16(a, f3, acc[3], 0, 0, 0);
    }

    // ---- Epilogue: out[c,q] = acc + s_u[q] ----
    float* __restrict__ outb = out + ((size_t)(b * Cn + c0 + wv * 16)) * Qn;
#pragma unroll
    for (int n = 0; n < 4; ++n) {
        const int q = n * 16 + ql;
        const float s = su_l[q];
#pragma unroll
        for (int rr = 0; rr < 4; ++rr)
            outb[(size_t)(hh * 4 + rr) * Qn + q] = acc[n][rr] + s;
    }
}

extern "C" void kernel_launch(void* const* d_in, const int* in_sizes, int n_in,
                              void* d_out, int out_size, void* d_ws, size_t ws_size,
                              hipStream_t stream) {
    const float* H = (const float*)d_in[0];
    const float* U = (const float*)d_in[1];
    const float* w = (const float*)d_in[2];
    float* out = (float*)d_out;
    sim_kernel<<<dim3(256), dim3(512), 0, stream>>>(H, U, w, out);
}